// Round 10
// baseline (726.560 us; speedup 1.0000x reference)
//
#include <hip/hip_runtime.h>

// EncoderBlock: B=8, S=2048, D=1024, H=4096, single-head attn (scale AFTER softmax),
// LN -> QKV -> scores -> softmax*(1/32) -> PV -> MLP(Swish) -> +residual.
// Round 10: staging-LATENCY fix. 128x128 tile, BK=32, TRIPLE-buffered LDS (48 KiB)
// -> 3 blocks/CU. Tile t staged at iter t-2: ~2 iters x 3-block overlap hides the
// ~900cy L3-miss latency that capped MLP GEMMs at 37% MfmaUtil (R8/R9 evidence:
// L2-resident GEMMs fast, streaming GEMMs stuck, schedule/intensity tweaks null).
// WS = 190,840,832 B, overlay identical to R6/R8/R9.

#define Bb_ 8
#define Ss_ 2048
#define Dd_ 1024
#define Hh_ 4096

typedef __bf16 bf16;
typedef _Float16 f16;
typedef __attribute__((ext_vector_type(8))) __bf16 bf16x8;
typedef __attribute__((ext_vector_type(8))) _Float16 f16x8;
typedef __attribute__((ext_vector_type(4))) __bf16 bf16x4;
typedef __attribute__((ext_vector_type(4))) float f32x4;

enum { EPI_QKV = 0, EPI_F16 = 1, EPI_AOS = 2, EPI_SWISH = 3, EPI_RESID = 4 };

__device__ __forceinline__ void gload16(const bf16* g, bf16* l) {
  __builtin_amdgcn_global_load_lds(
      (const __attribute__((address_space(1))) void*)g,
      (__attribute__((address_space(3))) void*)l, 16, 0, 0);
}

typedef const __attribute__((address_space(3))) bf16 cl_bf16;
__device__ __forceinline__ bf16x8 dsr128(const bf16* p) {
  bf16x8 r;
  asm volatile("ds_read_b128 %0, %1" : "=v"(r) : "v"((cl_bf16*)p));
  return r;
}

#define BAR() __builtin_amdgcn_s_barrier()
#define LGKM0() asm volatile("s_waitcnt lgkmcnt(0)" ::: "memory")
#define VMC(n) asm volatile("s_waitcnt vmcnt(" #n ")" ::: "memory")
#define SCHED0() __builtin_amdgcn_sched_barrier(0)
#define SETP(x) __builtin_amdgcn_s_setprio(x)

// ---------- transpose-cast: W[K][N] f32 -> WT[N][K] bf16 ----------
__global__ __launch_bounds__(256) void tcast_k(const float* __restrict__ W,
                                               bf16* __restrict__ WT, int K, int N) {
  __shared__ float tile[32][33];
  const int tn0 = blockIdx.x * 32;
  const int tk0 = blockIdx.y * 32;
  const int t = threadIdx.x;
  const int c = t & 31;
  const int r4 = t >> 5;
#pragma unroll
  for (int i = 0; i < 4; i++) {
    int r = r4 + i * 8;
    tile[r][c] = W[(long)(tk0 + r) * N + (tn0 + c)];
  }
  __syncthreads();
#pragma unroll
  for (int i = 0; i < 4; i++) {
    int r = r4 + i * 8;
    WT[(long)(tn0 + r) * K + (tk0 + c)] = (bf16)tile[c][r];
  }
}

// ---------- fp16 transpose: v[z][2048][1024] -> vT[z][1024][2048] ----------
__global__ __launch_bounds__(256) void tbf16_k(const f16* __restrict__ V,
                                               f16* __restrict__ VT) {
  __shared__ f16 tile[64][72];
  const long z = blockIdx.z;
  const int n0 = blockIdx.x * 64;
  const int k0 = blockIdx.y * 64;
  const int t = threadIdx.x;
  const int r = t >> 3;
  const int c = (t & 7) * 8;
  const f16* Vb = V + z * (long)(Ss_ * Dd_);
  f16* VTb = VT + z * (long)(Dd_ * Ss_);
#pragma unroll
  for (int i = 0; i < 2; i++)
    *(f16x8*)&tile[r + i * 32][c] =
        *(const f16x8*)(Vb + (long)(k0 + r + i * 32) * Dd_ + n0 + c);
  __syncthreads();
#pragma unroll
  for (int i = 0; i < 2; i++) {
    const int n = r + i * 32;
    f16x8 ov;
#pragma unroll
    for (int j = 0; j < 8; j++) ov[j] = tile[c + j][n];
    *(f16x8*)(VTb + (long)(n0 + n) * Ss_ + k0 + c) = ov;
  }
}

// ---------- LayerNorm: x[row][1024] f32 -> xn bf16 ----------
__global__ __launch_bounds__(256) void ln_k(const float* __restrict__ x,
                                            const float* __restrict__ gamma,
                                            const float* __restrict__ beta,
                                            bf16* __restrict__ xn) {
  const long row = blockIdx.x;
  const float* xr = x + row * Dd_;
  const int t = threadIdx.x;
  float4 v = *(const float4*)(xr + t * 4);
  float s = v.x + v.y + v.z + v.w;
  float sq = v.x * v.x + v.y * v.y + v.z * v.z + v.w * v.w;
#pragma unroll
  for (int o = 32; o > 0; o >>= 1) {
    s += __shfl_down(s, o);
    sq += __shfl_down(sq, o);
  }
  __shared__ float ls[4], lq[4];
  const int wid = t >> 6;
  if ((t & 63) == 0) { ls[wid] = s; lq[wid] = sq; }
  __syncthreads();
  if (t == 0) {
    float S = ls[0] + ls[1] + ls[2] + ls[3];
    float Q = lq[0] + lq[1] + lq[2] + lq[3];
    float mu = S * (1.0f / Dd_);
    float var = Q * (1.0f / Dd_) - mu * mu;
    ls[0] = mu;
    lq[0] = rsqrtf(var + 1e-5f);
  }
  __syncthreads();
  const float mu = ls[0], rstd = lq[0];
  float4 g = *(const float4*)(gamma + t * 4);
  float4 be = *(const float4*)(beta + t * 4);
  bf16x4 ov;
  ov[0] = (bf16)((v.x - mu) * rstd * g.x + be.x);
  ov[1] = (bf16)((v.y - mu) * rstd * g.y + be.y);
  ov[2] = (bf16)((v.z - mu) * rstd * g.z + be.z);
  ov[3] = (bf16)((v.w - mu) * rstd * g.w + be.w);
  *(bf16x4*)(xn + row * Dd_ + t * 4) = ov;
}

// ---------- softmax: fp16 scores (two slabs) -> fp16 probs (UNSCALED), in place ----------
__global__ __launch_bounds__(256) void softmax16_k(f16* __restrict__ lo,
                                                   f16* __restrict__ hi) {
  const long row = blockIdx.x;
  const long z = row >> 11;
  f16* sr = (z < 4 ? lo + z * 4194304L : hi + (z - 4) * 4194304L) +
            (row & 2047) * (long)Ss_;
  const int t = threadIdx.x;
  f16x8 v = *(const f16x8*)(sr + t * 8);
  float f[8];
#pragma unroll
  for (int j = 0; j < 8; j++) f[j] = (float)v[j];
  float vm = f[0];
#pragma unroll
  for (int j = 1; j < 8; j++) vm = fmaxf(vm, f[j]);
  __shared__ float red[4];
#pragma unroll
  for (int o = 32; o > 0; o >>= 1) vm = fmaxf(vm, __shfl_xor(vm, o));
  const int wid = t >> 6;
  if ((t & 63) == 0) red[wid] = vm;
  __syncthreads();
  vm = fmaxf(fmaxf(red[0], red[1]), fmaxf(red[2], red[3]));
  float e[8], s = 0.f;
#pragma unroll
  for (int j = 0; j < 8; j++) { e[j] = __expf(f[j] - vm); s += e[j]; }
#pragma unroll
  for (int o = 32; o > 0; o >>= 1) s += __shfl_xor(s, o);
  __syncthreads();
  if ((t & 63) == 0) red[wid] = s;
  __syncthreads();
  s = red[0] + red[1] + red[2] + red[3];
  const float rs = 1.0f / s;  // 1/32 applied in PV epilogue
  f16x8 ov;
#pragma unroll
  for (int j = 0; j < 8; j++) ov[j] = (f16)(e[j] * rs);
  *(f16x8*)(sr + t * 8) = ov;
}

// ====== 128x128xK GEMM, BK=32, TRIPLE-buffer 48KiB LDS, 4 waves, 3 blocks/CU ======
// C = A[M][K] * B[N][K]^T. DT=0 bf16 MFMA, DT=1 f16 MFMA.
// LDS: L[buf3][A 128x32 | B 128x32], swizzle as R9 (verified 0 conflicts):
// logical (r,k): elem r*32 + (kslot ^ ((r>>1)&3))*8+..; stage pre-swizzles GLOBAL col
// 8*((l&3)^((l>>3)&3)), gload_lds dest linear (rule 21 both-sides).
// Pipeline: tile t staged at iter t-2 (3 bufs). Per iter:
//   BAR (certifies all waves drained reads of t-1; its buf[(t+2)%3] is now dead)
//   STAGE(t+2 -> buf[(t+2)%3])            (4 gloads/wave)
//   vmcnt(8)  (own stage-t loads landed: 8 = stages t+1,t+2 outstanding)
//   BAR (all waves' stage-t landed)
//   8x ds_read(buf t) ; lgkm0 ; 16 MFMA
// Tail: t+2>=NT -> no stage, vmcnt(4) then vmcnt(0).
template <int EPI, int DT>
__global__ __launch_bounds__(256, 3) void gemm3_k(
    const bf16* __restrict__ Ab, const bf16* __restrict__ Bbp, void* __restrict__ Cb,
    const float* __restrict__ bias, const float* __restrict__ resid,
    int K, int lda, int ldb, int ldc, long astr, long bstr, long cstr) {
  extern __shared__ bf16 L[];  // 3 * 8192 elems = 48 KiB
  const int t = threadIdx.x;
  const int lane = t & 63;
  const int w = t >> 6;             // 0..3
  const int wm = w >> 1, wn = w & 1;

  // bijective XCD swizzle (all grids have (gx*gy)%8==0)
  const int gx = gridDim.x;
  const int nwg = gx * gridDim.y;
  const int dd = blockIdx.y * gx + blockIdx.x;
  const int Lid = (dd & 7) * (nwg >> 3) + (dd >> 3);
  const int m0 = (Lid / gx) * 128;
  const int n0 = (Lid % gx) * 128;

  const long z = blockIdx.z;
  const bf16* A;
  if constexpr (EPI == EPI_AOS) {
    A = (z < 4 ? Ab + z * astr : (const bf16*)bias + (z - 4) * astr);
  } else if constexpr (EPI == EPI_RESID) {
    const long qo[4] = {0, 33554432, 50331648, 67108864};  // h quarters (elem offs)
    A = Ab + qo[m0 >> 12] - (long)(m0 & ~4095) * lda;
  } else {
    A = Ab + z * astr;
  }
  const bf16* Bp = Bbp + z * bstr;

  // staging: chunk = 16 rows x 32k = 1 KB; A,B each 8 chunks; wave stages A,B chunks 2w,2w+1
  const int lrow = lane >> 2;                          // row within chunk
  const int sc = 8 * ((lane & 3) ^ ((lane >> 3) & 3)); // pre-swizzled k-col
  const bf16* gA[2];
  const bf16* gB[2];
#pragma unroll
  for (int j = 0; j < 2; ++j) {
    gA[j] = A + (long)(m0 + (w * 2 + j) * 16 + lrow) * lda + sc;
    gB[j] = Bp + (long)(n0 + (w * 2 + j) * 16 + lrow) * ldb + sc;
  }

#define STAGE(buf, tau)                                                          \
  do {                                                                           \
    _Pragma("unroll") for (int j_ = 0; j_ < 2; ++j_)                             \
        gload16(gA[j_] + (long)(tau) * 32,                                       \
                &L[(buf)*8192 + (w * 2 + j_) * 512]);                            \
    _Pragma("unroll") for (int j_ = 0; j_ < 2; ++j_)                             \
        gload16(gB[j_] + (long)(tau) * 32,                                       \
                &L[(buf)*8192 + 4096 + (w * 2 + j_) * 512]);                     \
  } while (0)

  // fragment reads: A rows wm*64+q*16+rA, B rows wn*64+p*16+rA; K=32 = one kstep
  const int rA = lane & 15;
  const int kk0 = (lane >> 4) * 8;
  const int xorv = ((rA >> 1) & 3) * 8;

#define READ_ALL(base)                                                           \
  _Pragma("unroll") for (int q_ = 0; q_ < 4; ++q_)                               \
      a[q_] = dsr128(&L[(base) + (wm * 64 + q_ * 16 + rA) * 32 + (kk0 ^ xorv)]); \
  _Pragma("unroll") for (int p_ = 0; p_ < 4; ++p_)                               \
      b[p_] = dsr128(&L[(base) + 4096 + (wn * 64 + p_ * 16 + rA) * 32 +          \
                        (kk0 ^ xorv)]);
#define MM(av, bv, cv)                                                           \
  (DT ? __builtin_amdgcn_mfma_f32_16x16x32_f16(                                  \
            __builtin_bit_cast(f16x8, av), __builtin_bit_cast(f16x8, bv), cv,    \
            0, 0, 0)                                                             \
      : __builtin_amdgcn_mfma_f32_16x16x32_bf16(av, bv, cv, 0, 0, 0))

  f32x4 acc[4][4] = {};
  bf16x8 a[4], b[4];

  // prologue: stage tiles 0,1 into bufs 0,1
  STAGE(0, 0);
  STAGE(1, 1);

  const int NT = K >> 5;
  int cur = 0, nxt2 = 2;  // buf index of tile tt, and of tile tt+2
  for (int tt = 0; tt < NT; ++tt) {
    BAR();  // all waves drained reads of tt-1 (lgkm0 precedes their MFMA) -> buf[nxt2] dead
    if (tt + 2 < NT) {
      STAGE(nxt2, tt + 2);
      VMC(8);   // own stage-tt landed (stages tt+1, tt+2 = 8 loads may fly)
    } else if (tt + 1 < NT) {
      VMC(4);   // only stage tt+1 outstanding
    } else {
      VMC(0);
    }
    BAR();  // all waves' stage-tt landed
    READ_ALL(cur * 8192);
    LGKM0();
    SCHED0();
    SETP(1);
#pragma unroll
    for (int q = 0; q < 4; ++q)
#pragma unroll
      for (int p = 0; p < 4; ++p)
        acc[q][p] = MM(a[q], b[p], acc[q][p]);
    SETP(0);
    cur = (cur == 2) ? 0 : cur + 1;
    nxt2 = (nxt2 == 2) ? 0 : nxt2 + 1;
  }

  // epilogue: C/D layout col=lane&15, row=(lane>>4)*4+j; wave tile 64x64
  const int row0 = m0 + wm * 64;
  const int col0 = n0 + wn * 64;
  const int cl = lane & 15;
  const int rg = (lane >> 4) * 4;
#pragma unroll
  for (int mi = 0; mi < 4; mi++) {
#pragma unroll
    for (int ni = 0; ni < 4; ni++) {
#pragma unroll
      for (int j = 0; j < 4; j++) {
        const long gm = row0 + mi * 16 + rg + j;
        const int gn = col0 + ni * 16 + cl;
        float val = acc[mi][ni][j];
        if constexpr (EPI == EPI_QKV) {
          if (z < 2) {
            ((bf16*)Cb)[z * cstr + gm * ldc + gn] = (bf16)val;   // q,k bf16
          } else {
            ((f16*)resid)[gm * (long)ldc + gn] = (f16)val;       // v rows fp16
          }
        } else if constexpr (EPI == EPI_F16) {
          // scores: z<4 -> Cb (scores_lo), z>=4 -> bias ptr (scores_hi)
          f16* dst = (z < 4) ? (f16*)Cb : (f16*)bias;
          dst[(z & 3) * cstr + gm * ldc + gn] = (f16)val;
        } else if constexpr (EPI == EPI_AOS) {
          ((bf16*)Cb)[z * cstr + gm * ldc + gn] = (bf16)(val * 0.03125f);
        } else if constexpr (EPI == EPI_SWISH) {
          const long qoc[4] = {0, 33554432, 50331648, 67108864};
          bf16* hq = (bf16*)Cb + qoc[m0 >> 12];
          float hv = val + bias[gn];
          hq[(long)(gm & 4095) * ldc + gn] = (bf16)(hv / (1.0f + __expf(-hv)));
        } else {  // EPI_RESID
          ((float*)Cb)[gm * (long)ldc + gn] = val + bias[gn] + resid[gm * (long)ldc + gn];
        }
      }
    }
  }
#undef STAGE
#undef READ_ALL
#undef MM
}

extern "C" void kernel_launch(void* const* d_in, const int* in_sizes, int n_in,
                              void* d_out, int out_size, void* d_ws, size_t ws_size,
                              hipStream_t stream) {
  const float* x  = (const float*)d_in[0];
  const float* g  = (const float*)d_in[1];
  const float* be = (const float*)d_in[2];
  const float* Wq = (const float*)d_in[3];
  const float* Wk = (const float*)d_in[4];
  const float* Wv = (const float*)d_in[5];
  const float* W1 = (const float*)d_in[6];
  const float* b1 = (const float*)d_in[7];
  const float* W2 = (const float*)d_in[8];
  const float* b2 = (const float*)d_in[9];

  hipFuncSetAttribute((const void*)&gemm3_k<EPI_QKV, 0>,
                      hipFuncAttributeMaxDynamicSharedMemorySize, 49152);
  hipFuncSetAttribute((const void*)&gemm3_k<EPI_F16, 0>,
                      hipFuncAttributeMaxDynamicSharedMemorySize, 49152);
  hipFuncSetAttribute((const void*)&gemm3_k<EPI_AOS, 1>,
                      hipFuncAttributeMaxDynamicSharedMemorySize, 49152);
  hipFuncSetAttribute((const void*)&gemm3_k<EPI_SWISH, 0>,
                      hipFuncAttributeMaxDynamicSharedMemorySize, 49152);
  hipFuncSetAttribute((const void*)&gemm3_k<EPI_RESID, 0>,
                      hipFuncAttributeMaxDynamicSharedMemorySize, 49152);

  // ---- workspace overlay (bytes); identical to R6/R8/R9 ----
  char* ws = (char*)d_ws;
  bf16* xn        = (bf16*)(ws + 0);
  f16*  scores_lo = (f16*)(ws + 0);            // z=0..3 after xn dies
  bf16* q         = (bf16*)(ws + 33554432);
  bf16* ao        = (bf16*)(ws + 33554432);    // after q dies
  bf16* kk        = (bf16*)(ws + 67108864);
  f16*  vT        = (f16*)(ws + 100663296);
  f16*  vrows     = (f16*)(ws + 134217728);
  f16*  scores_hi = (f16*)(ws + 134217728);    // z=4..7 after vrows dies
  bf16* wqT       = (bf16*)(ws + 167772160);
  bf16* w1T       = (bf16*)(ws + 174063616);
  bf16* w2T       = (bf16*)(ws + 182452224);
  // h quarters at byte offsets {0, 67108864, 100663296, 134217728} (EPI_SWISH/RESID).

  tcast_k<<<dim3(32, 32), 256, 0, stream>>>(Wq, wqT, 1024, 1024);
  tcast_k<<<dim3(32, 32), 256, 0, stream>>>(Wk, wqT + 1048576, 1024, 1024);
  tcast_k<<<dim3(32, 32), 256, 0, stream>>>(Wv, wqT + 2097152, 1024, 1024);
  tcast_k<<<dim3(128, 32), 256, 0, stream>>>(W1, w1T, 1024, 4096);
  tcast_k<<<dim3(32, 128), 256, 0, stream>>>(W2, w2T, 4096, 1024);

  ln_k<<<16384, 256, 0, stream>>>(x, g, be, xn);

  // QKV: z=0,1 -> q,k bf16; z=2 -> v rows fp16 via resid ptr
  gemm3_k<EPI_QKV, 0><<<dim3(8, 128, 3), 256, 49152, stream>>>(
      xn, wqT, q, nullptr, (const float*)vrows, 1024, 1024, 1024, 1024,
      0L, 1048576L, 16777216L);

  tbf16_k<<<dim3(16, 32, 8), 256, 0, stream>>>(vrows, vT);

  // scores: single launch, all 8 batches; slab-split in epilogue (hi via bias param)
  gemm3_k<EPI_F16, 0><<<dim3(16, 16, 8), 256, 49152, stream>>>(
      q, kk, scores_lo, (const float*)scores_hi, nullptr,
      1024, 1024, 1024, 2048, 2097152L, 2097152L, 4194304L);

  softmax16_k<<<16384, 256, 0, stream>>>(scores_lo, scores_hi);

  // PV: single launch over all 8 batches; A slab-split inside kernel (f16 MFMA)
  gemm3_k<EPI_AOS, 1><<<dim3(8, 16, 8), 256, 49152, stream>>>(
      (const bf16*)scores_lo, (const bf16*)vT, ao, (const float*)scores_hi, nullptr,
      2048, 2048, 2048, 1024, 4194304L, 2097152L, 2097152L);

  // MLP1: h (quartered) = swish(ao @ W1 + b1)
  gemm3_k<EPI_SWISH, 0><<<dim3(32, 128, 1), 256, 49152, stream>>>(
      ao, w1T, ws, b1, nullptr, 1024, 1024, 1024, 4096, 0L, 0L, 0L);
  // MLP2: out = h @ W2 + b2 + x (A from h quarters)
  gemm3_k<EPI_RESID, 0><<<dim3(8, 128, 1), 256, 49152, stream>>>(
      (const bf16*)ws, w2T, d_out, b2, x, 4096, 4096, 4096, 1024, 0L, 0L, 0L);
}

// Round 11
// 607.995 us; speedup vs baseline: 1.1950x; 1.1950x over previous
//
#include <hip/hip_runtime.h>

// EncoderBlock: B=8, S=2048, D=1024, H=4096, single-head attn (scale AFTER softmax),
// LN -> QKV -> scores -> softmax*(1/32) -> PV -> MLP(Swish) -> +residual.
// Round 11: R8 base (614us, best) with ONE change: compiler-managed LDS fragment reads
// (plain C++ instead of inline-asm dsr128 + lgkm0 + sched_barrier). Lets hipcc fold
// ds_read offset immediates (kills per-read address VALU) and emit counted lgkmcnt
// waits so MFMAs overlap in-flight reads (m97 behavior). Loop: STAGE(t+1) -> READS(t)
// -> MFMA -> __syncthreads(). WS = 190,840,832 B, overlay identical to R6/R8.

#define Bb_ 8
#define Ss_ 2048
#define Dd_ 1024
#define Hh_ 4096

typedef __bf16 bf16;
typedef _Float16 f16;
typedef __attribute__((ext_vector_type(8))) __bf16 bf16x8;
typedef __attribute__((ext_vector_type(8))) _Float16 f16x8;
typedef __attribute__((ext_vector_type(4))) __bf16 bf16x4;
typedef __attribute__((ext_vector_type(4))) float f32x4;

enum { EPI_QKV = 0, EPI_F16 = 1, EPI_AOS = 2, EPI_SWISH = 3, EPI_RESID = 4 };

__device__ __forceinline__ void gload16(const bf16* g, bf16* l) {
  __builtin_amdgcn_global_load_lds(
      (const __attribute__((address_space(1))) void*)g,
      (__attribute__((address_space(3))) void*)l, 16, 0, 0);
}

#define SETP(x) __builtin_amdgcn_s_setprio(x)

// ---------- transpose-cast: W[K][N] f32 -> WT[N][K] bf16 ----------
__global__ __launch_bounds__(256) void tcast_k(const float* __restrict__ W,
                                               bf16* __restrict__ WT, int K, int N) {
  __shared__ float tile[32][33];
  const int tn0 = blockIdx.x * 32;
  const int tk0 = blockIdx.y * 32;
  const int t = threadIdx.x;
  const int c = t & 31;
  const int r4 = t >> 5;
#pragma unroll
  for (int i = 0; i < 4; i++) {
    int r = r4 + i * 8;
    tile[r][c] = W[(long)(tk0 + r) * N + (tn0 + c)];
  }
  __syncthreads();
#pragma unroll
  for (int i = 0; i < 4; i++) {
    int r = r4 + i * 8;
    WT[(long)(tn0 + r) * K + (tk0 + c)] = (bf16)tile[c][r];
  }
}

// ---------- fp16 transpose: v[z][2048][1024] -> vT[z][1024][2048] ----------
__global__ __launch_bounds__(256) void tbf16_k(const f16* __restrict__ V,
                                               f16* __restrict__ VT) {
  __shared__ f16 tile[64][72];
  const long z = blockIdx.z;
  const int n0 = blockIdx.x * 64;
  const int k0 = blockIdx.y * 64;
  const int t = threadIdx.x;
  const int r = t >> 3;
  const int c = (t & 7) * 8;
  const f16* Vb = V + z * (long)(Ss_ * Dd_);
  f16* VTb = VT + z * (long)(Dd_ * Ss_);
#pragma unroll
  for (int i = 0; i < 2; i++)
    *(f16x8*)&tile[r + i * 32][c] =
        *(const f16x8*)(Vb + (long)(k0 + r + i * 32) * Dd_ + n0 + c);
  __syncthreads();
#pragma unroll
  for (int i = 0; i < 2; i++) {
    const int n = r + i * 32;
    f16x8 ov;
#pragma unroll
    for (int j = 0; j < 8; j++) ov[j] = tile[c + j][n];
    *(f16x8*)(VTb + (long)(n0 + n) * Ss_ + k0 + c) = ov;
  }
}

// ---------- LayerNorm: x[row][1024] f32 -> xn bf16 ----------
__global__ __launch_bounds__(256) void ln_k(const float* __restrict__ x,
                                            const float* __restrict__ gamma,
                                            const float* __restrict__ beta,
                                            bf16* __restrict__ xn) {
  const long row = blockIdx.x;
  const float* xr = x + row * Dd_;
  const int t = threadIdx.x;
  float4 v = *(const float4*)(xr + t * 4);
  float s = v.x + v.y + v.z + v.w;
  float sq = v.x * v.x + v.y * v.y + v.z * v.z + v.w * v.w;
#pragma unroll
  for (int o = 32; o > 0; o >>= 1) {
    s += __shfl_down(s, o);
    sq += __shfl_down(sq, o);
  }
  __shared__ float ls[4], lq[4];
  const int wid = t >> 6;
  if ((t & 63) == 0) { ls[wid] = s; lq[wid] = sq; }
  __syncthreads();
  if (t == 0) {
    float S = ls[0] + ls[1] + ls[2] + ls[3];
    float Q = lq[0] + lq[1] + lq[2] + lq[3];
    float mu = S * (1.0f / Dd_);
    float var = Q * (1.0f / Dd_) - mu * mu;
    ls[0] = mu;
    lq[0] = rsqrtf(var + 1e-5f);
  }
  __syncthreads();
  const float mu = ls[0], rstd = lq[0];
  float4 g = *(const float4*)(gamma + t * 4);
  float4 be = *(const float4*)(beta + t * 4);
  bf16x4 ov;
  ov[0] = (bf16)((v.x - mu) * rstd * g.x + be.x);
  ov[1] = (bf16)((v.y - mu) * rstd * g.y + be.y);
  ov[2] = (bf16)((v.z - mu) * rstd * g.z + be.z);
  ov[3] = (bf16)((v.w - mu) * rstd * g.w + be.w);
  *(bf16x4*)(xn + row * Dd_ + t * 4) = ov;
}

// ---------- softmax: fp16 scores (two slabs) -> fp16 probs (UNSCALED), in place ----------
__global__ __launch_bounds__(256) void softmax16_k(f16* __restrict__ lo,
                                                   f16* __restrict__ hi) {
  const long row = blockIdx.x;
  const long z = row >> 11;
  f16* sr = (z < 4 ? lo + z * 4194304L : hi + (z - 4) * 4194304L) +
            (row & 2047) * (long)Ss_;
  const int t = threadIdx.x;
  f16x8 v = *(const f16x8*)(sr + t * 8);
  float f[8];
#pragma unroll
  for (int j = 0; j < 8; j++) f[j] = (float)v[j];
  float vm = f[0];
#pragma unroll
  for (int j = 1; j < 8; j++) vm = fmaxf(vm, f[j]);
  __shared__ float red[4];
#pragma unroll
  for (int o = 32; o > 0; o >>= 1) vm = fmaxf(vm, __shfl_xor(vm, o));
  const int wid = t >> 6;
  if ((t & 63) == 0) red[wid] = vm;
  __syncthreads();
  vm = fmaxf(fmaxf(red[0], red[1]), fmaxf(red[2], red[3]));
  float e[8], s = 0.f;
#pragma unroll
  for (int j = 0; j < 8; j++) { e[j] = __expf(f[j] - vm); s += e[j]; }
#pragma unroll
  for (int o = 32; o > 0; o >>= 1) s += __shfl_xor(s, o);
  __syncthreads();
  if ((t & 63) == 0) red[wid] = s;
  __syncthreads();
  s = red[0] + red[1] + red[2] + red[3];
  const float rs = 1.0f / s;  // 1/32 applied in PV epilogue
  f16x8 ov;
#pragma unroll
  for (int j = 0; j < 8; j++) ov[j] = (f16)(e[j] * rs);
  *(f16x8*)(sr + t * 8) = ov;
}

// ========== 128x128xK GEMM, BK=64, dbuf 64KiB LDS, 4 waves, 2 blocks/CU ==========
// C = A[M][K] * B[N][K]^T. DT=0 bf16 MFMA, DT=1 f16 MFMA (bytes staged either way).
// LDS: L[buf2][op2][128*64] swizzled: (r,k) at elem r*64 + (k ^ ((r&7)*8));
// staged via pre-swizzled GLOBAL source + linear gload_lds dest (rule 21).
// R11: fragment reads are PLAIN C++ (compiler folds ds offsets, emits counted
// lgkmcnt waits -> MFMA overlaps in-flight reads). One __syncthreads per K-tile
// (its builtin vmcnt(0)+lgkmcnt(0)+barrier provides the staging/read fences R8
// did manually). Hazards: stage(t+1) targets buf^1 whose reads completed before
// the PREVIOUS barrier; barrier at iter end makes stage(t+1) collective-visible.
template <int EPI, int DT>
__global__ __launch_bounds__(256, 2) void gemmdb_k(
    const bf16* __restrict__ Ab, const bf16* __restrict__ Bbp, void* __restrict__ Cb,
    const float* __restrict__ bias, const float* __restrict__ resid,
    int K, int lda, int ldb, int ldc, long astr, long bstr, long cstr) {
  extern __shared__ bf16 L[];  // 2*2*8192 elems = 64 KiB
  const int t = threadIdx.x;
  const int lane = t & 63;
  const int w = t >> 6;             // 0..3
  const int wm = w >> 1, wn = w & 1;

  // bijective XCD swizzle (all grids have (gx*gy)%8==0)
  const int gx = gridDim.x;
  const int nwg = gx * gridDim.y;
  const int dd = blockIdx.y * gx + blockIdx.x;
  const int Lid = (dd & 7) * (nwg >> 3) + (dd >> 3);
  const int m0 = (Lid / gx) * 128;
  const int n0 = (Lid % gx) * 128;

  const long z = blockIdx.z;
  const bf16* A;
  if constexpr (EPI == EPI_AOS) {
    A = (z < 4 ? Ab + z * astr : (const bf16*)bias + (z - 4) * astr);
  } else if constexpr (EPI == EPI_RESID) {
    const long qo[4] = {0, 33554432, 50331648, 67108864};  // h quarters (elem offs)
    A = Ab + qo[m0 >> 12] - (long)(m0 & ~4095) * lda;
  } else {
    A = Ab + z * astr;
  }
  const bf16* Bp = Bbp + z * bstr;

  // staging: 128 rows -> 16 chunks of 8 rows (1KB each); wave w stages A,B chunks 4w..4w+3.
  // lane l -> row chunk*8 + (l>>3); pre-swizzled source col = 8*((l&7)^(l>>3)).
  const int lrow = lane >> 3;
  const int sc = 8 * ((lane & 7) ^ lrow);
  const bf16* gA[4];
  const bf16* gB[4];
#pragma unroll
  for (int j = 0; j < 4; ++j) {
    const int r = (w * 4 + j) * 8 + lrow;
    gA[j] = A + (long)(m0 + r) * lda + sc;
    gB[j] = Bp + (long)(n0 + r) * ldb + sc;
  }

#define STAGE(buf, tau)                                                          \
  do {                                                                           \
    _Pragma("unroll") for (int j_ = 0; j_ < 4; ++j_)                             \
        gload16(gA[j_] + (long)(tau) * 64,                                       \
                &L[((buf)*2 + 0) * 8192 + (w * 4 + j_) * 512]);                  \
    _Pragma("unroll") for (int j_ = 0; j_ < 4; ++j_)                             \
        gload16(gB[j_] + (long)(tau) * 64,                                       \
                &L[((buf)*2 + 1) * 8192 + (w * 4 + j_) * 512]);                  \
  } while (0)

  // fragment reads: A rows wm*64.., B rows wn*64..; 16 plain b128 reads per K-tile
  const int rA = lane & 15;
  const int kk0 = (lane >> 4) * 8;
  const int xorv = (rA & 7) * 8;

#define READ_ALL(ab, bb)                                                         \
  _Pragma("unroll") for (int q_ = 0; q_ < 4; ++q_)                               \
  _Pragma("unroll") for (int ks_ = 0; ks_ < 2; ++ks_) {                          \
    a[q_][ks_] = *(const bf16x8*)&L[(ab) + (wm * 64 + q_ * 16 + rA) * 64 +       \
                                    ((ks_ * 32 + kk0) ^ xorv)];                  \
    b[q_][ks_] = *(const bf16x8*)&L[(bb) + (wn * 64 + q_ * 16 + rA) * 64 +       \
                                    ((ks_ * 32 + kk0) ^ xorv)];                  \
  }
#define MM(av, bv, cv)                                                           \
  (DT ? __builtin_amdgcn_mfma_f32_16x16x32_f16(                                  \
            __builtin_bit_cast(f16x8, av), __builtin_bit_cast(f16x8, bv), cv,    \
            0, 0, 0)                                                             \
      : __builtin_amdgcn_mfma_f32_16x16x32_bf16(av, bv, cv, 0, 0, 0))

  f32x4 acc[4][4] = {};
  bf16x8 a[4][2], b[4][2];

  // prologue: stage tile 0 into buf0
  STAGE(0, 0);
  __syncthreads();

  const int NT = K >> 6;
  for (int tt = 0; tt < NT; ++tt) {
    const int cur = tt & 1;
    const int ab = (cur * 2 + 0) * 8192;
    const int bb = (cur * 2 + 1) * 8192;
    const bool nf = (tt + 1 < NT);
    if (nf) STAGE(cur ^ 1, tt + 1);
    READ_ALL(ab, bb);
    SETP(1);
#pragma unroll
    for (int ks = 0; ks < 2; ++ks)
#pragma unroll
      for (int q = 0; q < 4; ++q)
#pragma unroll
        for (int p = 0; p < 4; ++p)
          acc[q][p] = MM(a[q][ks], b[p][ks], acc[q][p]);
    SETP(0);
    __syncthreads();  // vmcnt(0)+lgkmcnt(0)+barrier: stage(t+1) visible, reads drained
  }

  // epilogue: C/D layout col=lane&15, row=(lane>>4)*4+j
  const int row0 = m0 + wm * 64;
  const int col0 = n0 + wn * 64;
  const int cl = lane & 15;
  const int rg = (lane >> 4) * 4;
#pragma unroll
  for (int mi = 0; mi < 4; mi++) {
#pragma unroll
    for (int ni = 0; ni < 4; ni++) {
#pragma unroll
      for (int j = 0; j < 4; j++) {
        const long gm = row0 + mi * 16 + rg + j;
        const int gn = col0 + ni * 16 + cl;
        float val = acc[mi][ni][j];
        if constexpr (EPI == EPI_QKV) {
          if (z < 2) {
            ((bf16*)Cb)[z * cstr + gm * ldc + gn] = (bf16)val;   // q,k bf16
          } else {
            ((f16*)resid)[gm * (long)ldc + gn] = (f16)val;       // v rows fp16
          }
        } else if constexpr (EPI == EPI_F16) {
          ((f16*)Cb)[z * cstr + gm * ldc + gn] = (f16)val;
        } else if constexpr (EPI == EPI_AOS) {
          ((bf16*)Cb)[z * cstr + gm * ldc + gn] = (bf16)(val * 0.03125f);
        } else if constexpr (EPI == EPI_SWISH) {
          const long qoc[4] = {0, 33554432, 50331648, 67108864};
          bf16* hq = (bf16*)Cb + qoc[m0 >> 12];
          float hv = val + bias[gn];
          hq[(long)(gm & 4095) * ldc + gn] = (bf16)(hv / (1.0f + __expf(-hv)));
        } else {  // EPI_RESID
          ((float*)Cb)[gm * (long)ldc + gn] = val + bias[gn] + resid[gm * (long)ldc + gn];
        }
      }
    }
  }
#undef STAGE
#undef READ_ALL
#undef MM
}

extern "C" void kernel_launch(void* const* d_in, const int* in_sizes, int n_in,
                              void* d_out, int out_size, void* d_ws, size_t ws_size,
                              hipStream_t stream) {
  const float* x  = (const float*)d_in[0];
  const float* g  = (const float*)d_in[1];
  const float* be = (const float*)d_in[2];
  const float* Wq = (const float*)d_in[3];
  const float* Wk = (const float*)d_in[4];
  const float* Wv = (const float*)d_in[5];
  const float* W1 = (const float*)d_in[6];
  const float* b1 = (const float*)d_in[7];
  const float* W2 = (const float*)d_in[8];
  const float* b2 = (const float*)d_in[9];

  hipFuncSetAttribute((const void*)&gemmdb_k<EPI_QKV, 0>,
                      hipFuncAttributeMaxDynamicSharedMemorySize, 65536);
  hipFuncSetAttribute((const void*)&gemmdb_k<EPI_F16, 0>,
                      hipFuncAttributeMaxDynamicSharedMemorySize, 65536);
  hipFuncSetAttribute((const void*)&gemmdb_k<EPI_AOS, 1>,
                      hipFuncAttributeMaxDynamicSharedMemorySize, 65536);
  hipFuncSetAttribute((const void*)&gemmdb_k<EPI_SWISH, 0>,
                      hipFuncAttributeMaxDynamicSharedMemorySize, 65536);
  hipFuncSetAttribute((const void*)&gemmdb_k<EPI_RESID, 0>,
                      hipFuncAttributeMaxDynamicSharedMemorySize, 65536);

  // ---- workspace overlay (bytes); identical to R6/R8 ----
  char* ws = (char*)d_ws;
  bf16* xn        = (bf16*)(ws + 0);
  f16*  scores_lo = (f16*)(ws + 0);            // z=0..3 after xn dies
  bf16* q         = (bf16*)(ws + 33554432);
  bf16* ao        = (bf16*)(ws + 33554432);    // after q dies
  bf16* kk        = (bf16*)(ws + 67108864);
  f16*  vT        = (f16*)(ws + 100663296);
  f16*  vrows     = (f16*)(ws + 134217728);
  f16*  scores_hi = (f16*)(ws + 134217728);    // z=4..7 after vrows dies
  bf16* wqT       = (bf16*)(ws + 167772160);
  bf16* w1T       = (bf16*)(ws + 174063616);
  bf16* w2T       = (bf16*)(ws + 182452224);
  // h quarters at byte offsets {0, 67108864, 100663296, 134217728} (EPI_SWISH/RESID).

  tcast_k<<<dim3(32, 32), 256, 0, stream>>>(Wq, wqT, 1024, 1024);
  tcast_k<<<dim3(32, 32), 256, 0, stream>>>(Wk, wqT + 1048576, 1024, 1024);
  tcast_k<<<dim3(32, 32), 256, 0, stream>>>(Wv, wqT + 2097152, 1024, 1024);
  tcast_k<<<dim3(128, 32), 256, 0, stream>>>(W1, w1T, 1024, 4096);
  tcast_k<<<dim3(32, 128), 256, 0, stream>>>(W2, w2T, 4096, 1024);

  ln_k<<<16384, 256, 0, stream>>>(x, g, be, xn);

  // QKV: z=0,1 -> q,k bf16; z=2 -> v rows fp16 via resid ptr
  gemmdb_k<EPI_QKV, 0><<<dim3(8, 128, 3), 256, 65536, stream>>>(
      xn, wqT, q, nullptr, (const float*)vrows, 1024, 1024, 1024, 1024,
      0L, 1048576L, 16777216L);

  tbf16_k<<<dim3(16, 32, 8), 256, 0, stream>>>(vrows, vT);

  // scores: two fp16 slabs
  gemmdb_k<EPI_F16, 0><<<dim3(16, 16, 4), 256, 65536, stream>>>(
      q, kk, scores_lo, nullptr, nullptr,
      1024, 1024, 1024, 2048, 2097152L, 2097152L, 4194304L);
  gemmdb_k<EPI_F16, 0><<<dim3(16, 16, 4), 256, 65536, stream>>>(
      q + 4L * 2097152, kk + 4L * 2097152, scores_hi, nullptr, nullptr,
      1024, 1024, 1024, 2048, 2097152L, 2097152L, 4194304L);

  softmax16_k<<<16384, 256, 0, stream>>>(scores_lo, scores_hi);

  // PV: single launch over all 8 batches; A slab-split inside kernel (f16 MFMA)
  gemmdb_k<EPI_AOS, 1><<<dim3(8, 16, 8), 256, 65536, stream>>>(
      (const bf16*)scores_lo, (const bf16*)vT, ao, (const float*)scores_hi, nullptr,
      2048, 2048, 2048, 1024, 4194304L, 2097152L, 2097152L);

  // MLP1: h (quartered) = swish(ao @ W1 + b1)
  gemmdb_k<EPI_SWISH, 0><<<dim3(32, 128, 1), 256, 65536, stream>>>(
      ao, w1T, ws, b1, nullptr, 1024, 1024, 1024, 4096, 0L, 0L, 0L);
  // MLP2: out = h @ W2 + b2 + x (A from h quarters)
  gemmdb_k<EPI_RESID, 0><<<dim3(8, 128, 1), 256, 65536, stream>>>(
      (const bf16*)ws, w2T, d_out, b2, x, 4096, 4096, 4096, 1024, 0L, 0L, 0L);
}

// Round 12
// 593.775 us; speedup vs baseline: 1.2236x; 1.0239x over previous
//
#include <hip/hip_runtime.h>

// EncoderBlock: B=8, S=2048, D=1024, H=4096, single-head attn (scale AFTER softmax),
// LN -> QKV -> scores -> softmax*(1/32) -> PV -> MLP(Swish) -> +residual.
// Round 12: R11 base (608us) + ONE change: L2-aware band raster inside each XCD chunk.
// Same-XCD blocks previously swept n-major per m-row -> w1T (8MB) refetched through the
// 4MB XCD L2 every m-row (412MB L2-miss on MLP1 vs 40MB working set). Now bands of
// H=8 m-rows x all n-cols: A-band (2MB) L2-resident, B fetched once per band.
// WS = 190,840,832 B, overlay identical to R6/R8/R11.

#define Bb_ 8
#define Ss_ 2048
#define Dd_ 1024
#define Hh_ 4096

typedef __bf16 bf16;
typedef _Float16 f16;
typedef __attribute__((ext_vector_type(8))) __bf16 bf16x8;
typedef __attribute__((ext_vector_type(8))) _Float16 f16x8;
typedef __attribute__((ext_vector_type(4))) __bf16 bf16x4;
typedef __attribute__((ext_vector_type(4))) float f32x4;

enum { EPI_QKV = 0, EPI_F16 = 1, EPI_AOS = 2, EPI_SWISH = 3, EPI_RESID = 4 };

__device__ __forceinline__ void gload16(const bf16* g, bf16* l) {
  __builtin_amdgcn_global_load_lds(
      (const __attribute__((address_space(1))) void*)g,
      (__attribute__((address_space(3))) void*)l, 16, 0, 0);
}

#define SETP(x) __builtin_amdgcn_s_setprio(x)

// ---------- transpose-cast: W[K][N] f32 -> WT[N][K] bf16 ----------
__global__ __launch_bounds__(256) void tcast_k(const float* __restrict__ W,
                                               bf16* __restrict__ WT, int K, int N) {
  __shared__ float tile[32][33];
  const int tn0 = blockIdx.x * 32;
  const int tk0 = blockIdx.y * 32;
  const int t = threadIdx.x;
  const int c = t & 31;
  const int r4 = t >> 5;
#pragma unroll
  for (int i = 0; i < 4; i++) {
    int r = r4 + i * 8;
    tile[r][c] = W[(long)(tk0 + r) * N + (tn0 + c)];
  }
  __syncthreads();
#pragma unroll
  for (int i = 0; i < 4; i++) {
    int r = r4 + i * 8;
    WT[(long)(tn0 + r) * K + (tk0 + c)] = (bf16)tile[c][r];
  }
}

// ---------- fp16 transpose: v[z][2048][1024] -> vT[z][1024][2048] ----------
__global__ __launch_bounds__(256) void tbf16_k(const f16* __restrict__ V,
                                               f16* __restrict__ VT) {
  __shared__ f16 tile[64][72];
  const long z = blockIdx.z;
  const int n0 = blockIdx.x * 64;
  const int k0 = blockIdx.y * 64;
  const int t = threadIdx.x;
  const int r = t >> 3;
  const int c = (t & 7) * 8;
  const f16* Vb = V + z * (long)(Ss_ * Dd_);
  f16* VTb = VT + z * (long)(Dd_ * Ss_);
#pragma unroll
  for (int i = 0; i < 2; i++)
    *(f16x8*)&tile[r + i * 32][c] =
        *(const f16x8*)(Vb + (long)(k0 + r + i * 32) * Dd_ + n0 + c);
  __syncthreads();
#pragma unroll
  for (int i = 0; i < 2; i++) {
    const int n = r + i * 32;
    f16x8 ov;
#pragma unroll
    for (int j = 0; j < 8; j++) ov[j] = tile[c + j][n];
    *(f16x8*)(VTb + (long)(n0 + n) * Ss_ + k0 + c) = ov;
  }
}

// ---------- LayerNorm: x[row][1024] f32 -> xn bf16 ----------
__global__ __launch_bounds__(256) void ln_k(const float* __restrict__ x,
                                            const float* __restrict__ gamma,
                                            const float* __restrict__ beta,
                                            bf16* __restrict__ xn) {
  const long row = blockIdx.x;
  const float* xr = x + row * Dd_;
  const int t = threadIdx.x;
  float4 v = *(const float4*)(xr + t * 4);
  float s = v.x + v.y + v.z + v.w;
  float sq = v.x * v.x + v.y * v.y + v.z * v.z + v.w * v.w;
#pragma unroll
  for (int o = 32; o > 0; o >>= 1) {
    s += __shfl_down(s, o);
    sq += __shfl_down(sq, o);
  }
  __shared__ float ls[4], lq[4];
  const int wid = t >> 6;
  if ((t & 63) == 0) { ls[wid] = s; lq[wid] = sq; }
  __syncthreads();
  if (t == 0) {
    float S = ls[0] + ls[1] + ls[2] + ls[3];
    float Q = lq[0] + lq[1] + lq[2] + lq[3];
    float mu = S * (1.0f / Dd_);
    float var = Q * (1.0f / Dd_) - mu * mu;
    ls[0] = mu;
    lq[0] = rsqrtf(var + 1e-5f);
  }
  __syncthreads();
  const float mu = ls[0], rstd = lq[0];
  float4 g = *(const float4*)(gamma + t * 4);
  float4 be = *(const float4*)(beta + t * 4);
  bf16x4 ov;
  ov[0] = (bf16)((v.x - mu) * rstd * g.x + be.x);
  ov[1] = (bf16)((v.y - mu) * rstd * g.y + be.y);
  ov[2] = (bf16)((v.z - mu) * rstd * g.z + be.z);
  ov[3] = (bf16)((v.w - mu) * rstd * g.w + be.w);
  *(bf16x4*)(xn + row * Dd_ + t * 4) = ov;
}

// ---------- softmax: fp16 scores (two slabs) -> fp16 probs (UNSCALED), in place ----------
__global__ __launch_bounds__(256) void softmax16_k(f16* __restrict__ lo,
                                                   f16* __restrict__ hi) {
  const long row = blockIdx.x;
  const long z = row >> 11;
  f16* sr = (z < 4 ? lo + z * 4194304L : hi + (z - 4) * 4194304L) +
            (row & 2047) * (long)Ss_;
  const int t = threadIdx.x;
  f16x8 v = *(const f16x8*)(sr + t * 8);
  float f[8];
#pragma unroll
  for (int j = 0; j < 8; j++) f[j] = (float)v[j];
  float vm = f[0];
#pragma unroll
  for (int j = 1; j < 8; j++) vm = fmaxf(vm, f[j]);
  __shared__ float red[4];
#pragma unroll
  for (int o = 32; o > 0; o >>= 1) vm = fmaxf(vm, __shfl_xor(vm, o));
  const int wid = t >> 6;
  if ((t & 63) == 0) red[wid] = vm;
  __syncthreads();
  vm = fmaxf(fmaxf(red[0], red[1]), fmaxf(red[2], red[3]));
  float e[8], s = 0.f;
#pragma unroll
  for (int j = 0; j < 8; j++) { e[j] = __expf(f[j] - vm); s += e[j]; }
#pragma unroll
  for (int o = 32; o > 0; o >>= 1) s += __shfl_xor(s, o);
  __syncthreads();
  if ((t & 63) == 0) red[wid] = s;
  __syncthreads();
  s = red[0] + red[1] + red[2] + red[3];
  const float rs = 1.0f / s;  // 1/32 applied in PV epilogue
  f16x8 ov;
#pragma unroll
  for (int j = 0; j < 8; j++) ov[j] = (f16)(e[j] * rs);
  *(f16x8*)(sr + t * 8) = ov;
}

// ========== 128x128xK GEMM, BK=64, dbuf 64KiB LDS, 4 waves, 2 blocks/CU ==========
// C = A[M][K] * B[N][K]^T. DT=0 bf16 MFMA, DT=1 f16 MFMA (bytes staged either way).
// LDS: L[buf2][op2][128*64] swizzled: (r,k) at elem r*64 + (k ^ ((r&7)*8));
// staged via pre-swizzled GLOBAL source + linear gload_lds dest (rule 21).
// Loop: STAGE(t+1) -> plain-C++ READS(t) -> MFMA (compiler-interleaved) -> syncthreads.
// R12: XCD-chunked L2 band raster. XCD c owns tiles [c*cpx,(c+1)*cpx) = R m-rows;
// within the chunk, bands of H m-rows sweep all n: A-band L2-resident, B once/band.
template <int EPI, int DT>
__global__ __launch_bounds__(256, 2) void gemmdb_k(
    const bf16* __restrict__ Ab, const bf16* __restrict__ Bbp, void* __restrict__ Cb,
    const float* __restrict__ bias, const float* __restrict__ resid,
    int K, int lda, int ldb, int ldc, long astr, long bstr, long cstr) {
  extern __shared__ bf16 L[];  // 2*2*8192 elems = 64 KiB
  const int t = threadIdx.x;
  const int lane = t & 63;
  const int w = t >> 6;             // 0..3
  const int wm = w >> 1, wn = w & 1;

  // ---- XCD-chunked band raster (bijective; all grids: nwg%8==0, (cpx/gx)|R, H|R) ----
  const int gx = gridDim.x;                 // n tiles
  const int nwg = gx * gridDim.y;
  const int dd = blockIdx.y * gx + blockIdx.x;
  const int cpx = nwg >> 3;                 // tiles per XCD chunk
  const int xcd = dd & 7;                   // dispatch round-robins XCDs
  const int idx = dd >> 3;                  // 0..cpx-1 within chunk
  const int R = cpx / gx;                   // m-rows per chunk
  const int H = (R >= 8) ? 8 : R;           // band height (H | R for all our grids)
  const int bandsz = H * gx;
  const int bnd = idx / bandsz;
  const int rr = idx % bandsz;
  const int m_t = xcd * R + bnd * H + (rr % H);
  const int n_t = rr / H;
  const int m0 = m_t * 128;
  const int n0 = n_t * 128;

  const long z = blockIdx.z;
  const bf16* A;
  if constexpr (EPI == EPI_AOS) {
    A = (z < 4 ? Ab + z * astr : (const bf16*)bias + (z - 4) * astr);
  } else if constexpr (EPI == EPI_RESID) {
    const long qo[4] = {0, 33554432, 50331648, 67108864};  // h quarters (elem offs)
    A = Ab + qo[m0 >> 12] - (long)(m0 & ~4095) * lda;
  } else {
    A = Ab + z * astr;
  }
  const bf16* Bp = Bbp + z * bstr;

  // staging: 128 rows -> 16 chunks of 8 rows (1KB each); wave w stages A,B chunks 4w..4w+3.
  // lane l -> row chunk*8 + (l>>3); pre-swizzled source col = 8*((l&7)^(l>>3)).
  const int lrow = lane >> 3;
  const int sc = 8 * ((lane & 7) ^ lrow);
  const bf16* gA[4];
  const bf16* gB[4];
#pragma unroll
  for (int j = 0; j < 4; ++j) {
    const int r = (w * 4 + j) * 8 + lrow;
    gA[j] = A + (long)(m0 + r) * lda + sc;
    gB[j] = Bp + (long)(n0 + r) * ldb + sc;
  }

#define STAGE(buf, tau)                                                          \
  do {                                                                           \
    _Pragma("unroll") for (int j_ = 0; j_ < 4; ++j_)                             \
        gload16(gA[j_] + (long)(tau) * 64,                                       \
                &L[((buf)*2 + 0) * 8192 + (w * 4 + j_) * 512]);                  \
    _Pragma("unroll") for (int j_ = 0; j_ < 4; ++j_)                             \
        gload16(gB[j_] + (long)(tau) * 64,                                       \
                &L[((buf)*2 + 1) * 8192 + (w * 4 + j_) * 512]);                  \
  } while (0)

  // fragment reads: A rows wm*64.., B rows wn*64..; 16 plain b128 reads per K-tile
  const int rA = lane & 15;
  const int kk0 = (lane >> 4) * 8;
  const int xorv = (rA & 7) * 8;

#define READ_ALL(ab, bb)                                                         \
  _Pragma("unroll") for (int q_ = 0; q_ < 4; ++q_)                               \
  _Pragma("unroll") for (int ks_ = 0; ks_ < 2; ++ks_) {                          \
    a[q_][ks_] = *(const bf16x8*)&L[(ab) + (wm * 64 + q_ * 16 + rA) * 64 +       \
                                    ((ks_ * 32 + kk0) ^ xorv)];                  \
    b[q_][ks_] = *(const bf16x8*)&L[(bb) + (wn * 64 + q_ * 16 + rA) * 64 +       \
                                    ((ks_ * 32 + kk0) ^ xorv)];                  \
  }
#define MM(av, bv, cv)                                                           \
  (DT ? __builtin_amdgcn_mfma_f32_16x16x32_f16(                                  \
            __builtin_bit_cast(f16x8, av), __builtin_bit_cast(f16x8, bv), cv,    \
            0, 0, 0)                                                             \
      : __builtin_amdgcn_mfma_f32_16x16x32_bf16(av, bv, cv, 0, 0, 0))

  f32x4 acc[4][4] = {};
  bf16x8 a[4][2], b[4][2];

  // prologue: stage tile 0 into buf0
  STAGE(0, 0);
  __syncthreads();

  const int NT = K >> 6;
  for (int tt = 0; tt < NT; ++tt) {
    const int cur = tt & 1;
    const int ab = (cur * 2 + 0) * 8192;
    const int bb = (cur * 2 + 1) * 8192;
    const bool nf = (tt + 1 < NT);
    if (nf) STAGE(cur ^ 1, tt + 1);
    READ_ALL(ab, bb);
    SETP(1);
#pragma unroll
    for (int ks = 0; ks < 2; ++ks)
#pragma unroll
      for (int q = 0; q < 4; ++q)
#pragma unroll
        for (int p = 0; p < 4; ++p)
          acc[q][p] = MM(a[q][ks], b[p][ks], acc[q][p]);
    SETP(0);
    __syncthreads();  // vmcnt(0)+lgkmcnt(0)+barrier: stage(t+1) visible, reads drained
  }

  // epilogue: C/D layout col=lane&15, row=(lane>>4)*4+j
  const int row0 = m0 + wm * 64;
  const int col0 = n0 + wn * 64;
  const int cl = lane & 15;
  const int rg = (lane >> 4) * 4;
#pragma unroll
  for (int mi = 0; mi < 4; mi++) {
#pragma unroll
    for (int ni = 0; ni < 4; ni++) {
#pragma unroll
      for (int j = 0; j < 4; j++) {
        const long gm = row0 + mi * 16 + rg + j;
        const int gn = col0 + ni * 16 + cl;
        float val = acc[mi][ni][j];
        if constexpr (EPI == EPI_QKV) {
          if (z < 2) {
            ((bf16*)Cb)[z * cstr + gm * ldc + gn] = (bf16)val;   // q,k bf16
          } else {
            ((f16*)resid)[gm * (long)ldc + gn] = (f16)val;       // v rows fp16
          }
        } else if constexpr (EPI == EPI_F16) {
          ((f16*)Cb)[z * cstr + gm * ldc + gn] = (f16)val;
        } else if constexpr (EPI == EPI_AOS) {
          ((bf16*)Cb)[z * cstr + gm * ldc + gn] = (bf16)(val * 0.03125f);
        } else if constexpr (EPI == EPI_SWISH) {
          const long qoc[4] = {0, 67108864 / 2, 100663296 / 2, 134217728 / 2};
          bf16* hq = (bf16*)Cb + qoc[m0 >> 12];
          float hv = val + bias[gn];
          hq[(long)(gm & 4095) * ldc + gn] = (bf16)(hv / (1.0f + __expf(-hv)));
        } else {  // EPI_RESID
          ((float*)Cb)[gm * (long)ldc + gn] = val + bias[gn] + resid[gm * (long)ldc + gn];
        }
      }
    }
  }
#undef STAGE
#undef READ_ALL
#undef MM
}

extern "C" void kernel_launch(void* const* d_in, const int* in_sizes, int n_in,
                              void* d_out, int out_size, void* d_ws, size_t ws_size,
                              hipStream_t stream) {
  const float* x  = (const float*)d_in[0];
  const float* g  = (const float*)d_in[1];
  const float* be = (const float*)d_in[2];
  const float* Wq = (const float*)d_in[3];
  const float* Wk = (const float*)d_in[4];
  const float* Wv = (const float*)d_in[5];
  const float* W1 = (const float*)d_in[6];
  const float* b1 = (const float*)d_in[7];
  const float* W2 = (const float*)d_in[8];
  const float* b2 = (const float*)d_in[9];

  hipFuncSetAttribute((const void*)&gemmdb_k<EPI_QKV, 0>,
                      hipFuncAttributeMaxDynamicSharedMemorySize, 65536);
  hipFuncSetAttribute((const void*)&gemmdb_k<EPI_F16, 0>,
                      hipFuncAttributeMaxDynamicSharedMemorySize, 65536);
  hipFuncSetAttribute((const void*)&gemmdb_k<EPI_AOS, 1>,
                      hipFuncAttributeMaxDynamicSharedMemorySize, 65536);
  hipFuncSetAttribute((const void*)&gemmdb_k<EPI_SWISH, 0>,
                      hipFuncAttributeMaxDynamicSharedMemorySize, 65536);
  hipFuncSetAttribute((const void*)&gemmdb_k<EPI_RESID, 0>,
                      hipFuncAttributeMaxDynamicSharedMemorySize, 65536);

  // ---- workspace overlay (bytes); identical to R6/R8/R11 ----
  char* ws = (char*)d_ws;
  bf16* xn        = (bf16*)(ws + 0);
  f16*  scores_lo = (f16*)(ws + 0);            // z=0..3 after xn dies
  bf16* q         = (bf16*)(ws + 33554432);
  bf16* ao        = (bf16*)(ws + 33554432);    // after q dies
  bf16* kk        = (bf16*)(ws + 67108864);
  f16*  vT        = (f16*)(ws + 100663296);
  f16*  vrows     = (f16*)(ws + 134217728);
  f16*  scores_hi = (f16*)(ws + 134217728);    // z=4..7 after vrows dies
  bf16* wqT       = (bf16*)(ws + 167772160);
  bf16* w1T       = (bf16*)(ws + 174063616);
  bf16* w2T       = (bf16*)(ws + 182452224);
  // h quarters at byte offsets {0, 67108864, 100663296, 134217728} (EPI_SWISH/RESID).

  tcast_k<<<dim3(32, 32), 256, 0, stream>>>(Wq, wqT, 1024, 1024);
  tcast_k<<<dim3(32, 32), 256, 0, stream>>>(Wk, wqT + 1048576, 1024, 1024);
  tcast_k<<<dim3(32, 32), 256, 0, stream>>>(Wv, wqT + 2097152, 1024, 1024);
  tcast_k<<<dim3(128, 32), 256, 0, stream>>>(W1, w1T, 1024, 4096);
  tcast_k<<<dim3(32, 128), 256, 0, stream>>>(W2, w2T, 4096, 1024);

  ln_k<<<16384, 256, 0, stream>>>(x, g, be, xn);

  // QKV: z=0,1 -> q,k bf16; z=2 -> v rows fp16 via resid ptr
  gemmdb_k<EPI_QKV, 0><<<dim3(8, 128, 3), 256, 65536, stream>>>(
      xn, wqT, q, nullptr, (const float*)vrows, 1024, 1024, 1024, 1024,
      0L, 1048576L, 16777216L);

  tbf16_k<<<dim3(16, 32, 8), 256, 0, stream>>>(vrows, vT);

  // scores: two fp16 slabs
  gemmdb_k<EPI_F16, 0><<<dim3(16, 16, 4), 256, 65536, stream>>>(
      q, kk, scores_lo, nullptr, nullptr,
      1024, 1024, 1024, 2048, 2097152L, 2097152L, 4194304L);
  gemmdb_k<EPI_F16, 0><<<dim3(16, 16, 4), 256, 65536, stream>>>(
      q + 4L * 2097152, kk + 4L * 2097152, scores_hi, nullptr, nullptr,
      1024, 1024, 1024, 2048, 2097152L, 2097152L, 4194304L);

  softmax16_k<<<16384, 256, 0, stream>>>(scores_lo, scores_hi);

  // PV: single launch over all 8 batches; A slab-split inside kernel (f16 MFMA)
  gemmdb_k<EPI_AOS, 1><<<dim3(8, 16, 8), 256, 65536, stream>>>(
      (const bf16*)scores_lo, (const bf16*)vT, ao, (const float*)scores_hi, nullptr,
      2048, 2048, 2048, 1024, 4194304L, 2097152L, 2097152L);

  // MLP1: h (quartered) = swish(ao @ W1 + b1)
  gemmdb_k<EPI_SWISH, 0><<<dim3(32, 128, 1), 256, 65536, stream>>>(
      ao, w1T, ws, b1, nullptr, 1024, 1024, 1024, 4096, 0L, 0L, 0L);
  // MLP2: out = h @ W2 + b2 + x (A from h quarters)
  gemmdb_k<EPI_RESID, 0><<<dim3(8, 128, 1), 256, 65536, stream>>>(
      (const bf16*)ws, w2T, d_out, b2, x, 4096, 4096, 4096, 1024, 0L, 0L, 0L);
}